// Round 5
// baseline (1023.564 us; speedup 1.0000x reference)
//
#include <hip/hip_runtime.h>
#include <math.h>

// FastFourierConvolution: B=4, C=128, H=W=256. Cg=Cl=64, Ci=32.
// FU1: (B,32,256,256) -> rfft2 -> conv64x64+BN+relu -> herm irfft2
// FU2 (LFU): y_in[:,24:32] quadrant-stacked to (B,32,128,128), same pipeline, tiled 2x2.

#define PI2 6.283185307179586f

__device__ __forceinline__ void fma4(float4& a, float w, const float4& v) {
  a.x += w * v.x; a.y += w * v.y; a.z += w * v.z; a.w += w * v.w;
}
__device__ __forceinline__ float4 add4(const float4& a, const float4& b) {
  return make_float4(a.x + b.x, a.y + b.y, a.z + b.z, a.w + b.w);
}

// ---------------- FFT core: radix-2 DIT in LDS, blockDim == N/2 ----------------
template<int N, int LOG2N>
__device__ __forceinline__ void fft_stages(float* re, float* im, int tid, float sign) {
#pragma unroll
  for (int s = 1; s <= LOG2N; ++s) {
    __syncthreads();
    const int half = 1 << (s - 1);
    const int j = tid & (half - 1);
    const int i1 = ((tid >> (s - 1)) << s) + j;
    const int i2 = i1 + half;
    float ang = sign * (PI2 / (float)(1 << s)) * (float)j;
    float wr, wi;
    __sincosf(ang, &wi, &wr);
    float xr = re[i2], xi = im[i2];
    float vr = xr * wr - xi * wi;
    float vi = xr * wi + xi * wr;
    float ur = re[i1], ui = im[i1];
    re[i1] = ur + vr; im[i1] = ui + vi;
    re[i2] = ur - vr; im[i2] = ui - vi;
  }
  __syncthreads();
}

// row rfft: one block per row of length N (real) -> N/2+1 complex bins
template<int N, int LOG2N>
__global__ void rfft_rows(const float* __restrict__ src, float2* __restrict__ dst) {
  __shared__ float re[N], im[N];
  const int row = blockIdx.x;
  const int tid = threadIdx.x;  // N/2 threads
  const float* p = src + (size_t)row * N;
  for (int i = tid; i < N; i += N / 2) {
    int j = __brev((unsigned)i) >> (32 - LOG2N);
    re[j] = p[i];
    im[j] = 0.f;
  }
  fft_stages<N, LOG2N>(re, im, tid, -1.f);
  float2* q = dst + (size_t)row * (N / 2 + 1);
  for (int k = tid; k <= N / 2; k += N / 2) q[k] = make_float2(re[k], im[k]);
}

// LFU gather + row rfft (N=128): reads quadrants of y_in channels 24..31
__global__ void rfft_rows_lfu(const float* __restrict__ y_in, float2* __restrict__ dst) {
  __shared__ float re[128], im[128];
  const int bid = blockIdx.x;          // ((b*32+c2)*128 + h2)
  const int h2 = bid & 127;
  const int c2 = (bid >> 7) & 31;
  const int b  = bid >> 12;
  const int q = c2 >> 3, ch = c2 & 7;
  const int hs = ((q >> 1) << 7) + h2;
  const int ws0 = (q & 1) << 7;
  const float* p = y_in + (((size_t)(b * 32 + 24 + ch) * 256 + hs) * 256 + ws0);
  const int tid = threadIdx.x;  // 64
  for (int i = tid; i < 128; i += 64) {
    int j = __brev((unsigned)i) >> 25;
    re[j] = p[i];
    im[j] = 0.f;
  }
  fft_stages<128, 7>(re, im, tid, -1.f);
  float2* qp = dst + (size_t)bid * 65;
  for (int k = tid; k <= 64; k += 64) qp[k] = make_float2(re[k], im[k]);
}

// ---------------- tiled forward column FFT: block = 16 columns x N rows ----------------
template<int N, int LOG2N, int TW>
__global__ void cfft_cols_t(float2* __restrict__ data, int Wf, float sign, int tilesPerImg) {
  __shared__ float re[N][TW + 1], im[N][TW + 1];
  const int img = blockIdx.x / tilesPerImg;
  const int k0 = (blockIdx.x % tilesPerImg) * TW;
  const int cols = min(TW, Wf - k0);
  float2* base = data + (size_t)img * N * Wf + k0;
  const int t = threadIdx.x;
  const int c = t & (TW - 1);
  const int g = t >> 4;
  const bool act = (c < cols);
  for (int r = g; r < N; r += 16) {
    float2 v;
    if (act) v = base[(size_t)r * Wf + c];
    int j = __brev((unsigned)r) >> (32 - LOG2N);
    if (act) { re[j][c] = v.x; im[j][c] = v.y; }
  }
#pragma unroll
  for (int s = 1; s <= LOG2N; ++s) {
    __syncthreads();
    const int half = 1 << (s - 1);
    for (int bf = g; bf < N / 2; bf += 16) {
      if (!act) continue;
      const int j = bf & (half - 1);
      const int i1 = ((bf >> (s - 1)) << s) + j;
      const int i2 = i1 + half;
      float ang = sign * (PI2 / (float)(1 << s)) * (float)j;
      float wr, wi;
      __sincosf(ang, &wi, &wr);
      float xr = re[i2][c], xi = im[i2][c];
      float vr = xr * wr - xi * wi;
      float vi = xr * wi + xi * wr;
      float ur = re[i1][c], ui = im[i1][c];
      re[i1][c] = ur + vr; im[i1][c] = ui + vi;
      re[i2][c] = ur - vr; im[i2][c] = ui - vi;
    }
  }
  __syncthreads();
  for (int r = g; r < N; r += 16) {
    if (act) base[(size_t)r * Wf + c] = make_float2(re[r][c], im[r][c]);
  }
}

// ---------------- fused BN+relu+symmetrize + inverse column FFT ----------------
// reads Z (channel-major), applies scale/shift/relu, symmetrizes k=0/Nyquist, writes T columns
template<int N, int LOG2N, int TW>
__global__ void cfft_inv_bn(const float* __restrict__ Z, const float* __restrict__ scale,
                            const float* __restrict__ shift, float2* __restrict__ T,
                            int Wf, int tilesPerImg, int chs) {
  __shared__ float re[N][TW + 1], im[N][TW + 1];
  const int img = blockIdx.x / tilesPerImg;    // b*32 + cc
  const int b = img >> 5, cc = img & 31;
  const int k0 = (blockIdx.x % tilesPerImg) * TW;
  const int cols = min(TW, Wf - k0);
  const int t = threadIdx.x;
  const int c = t & (TW - 1);
  const int g = t >> 4;
  const bool act = (c < cols);
  const int kk = k0 + c;
  const float scr = scale[cc], sfr = shift[cc];
  const float sci = scale[cc + 32], sfi = shift[cc + 32];
  const float* Zr = Z + (size_t)cc * chs + (size_t)b * N * Wf;
  const float* Zi = Z + (size_t)(cc + 32) * chs + (size_t)b * N * Wf;
  const bool edge = (kk == 0 || kk == Wf - 1);
  for (int r = g; r < N; r += 16) {
    float vr = 0.f, vi = 0.f;
    if (act) {
      size_t p = (size_t)r * Wf + kk;
      float yr = fmaxf(Zr[p] * scr + sfr, 0.f);
      float yi = fmaxf(Zi[p] * sci + sfi, 0.f);
      if (edge) {
        int rm = (N - r) & (N - 1);
        size_t pm = (size_t)rm * Wf + kk;
        float yr2 = fmaxf(Zr[pm] * scr + sfr, 0.f);
        float yi2 = fmaxf(Zi[pm] * sci + sfi, 0.f);
        yr = 0.5f * (yr + yr2);
        yi = 0.5f * (yi - yi2);
      }
      vr = yr; vi = yi;
    }
    int j = __brev((unsigned)r) >> (32 - LOG2N);
    if (act) { re[j][c] = vr; im[j][c] = vi; }
  }
#pragma unroll
  for (int s = 1; s <= LOG2N; ++s) {
    __syncthreads();
    const int half = 1 << (s - 1);
    for (int bf = g; bf < N / 2; bf += 16) {
      if (!act) continue;
      const int jq = bf & (half - 1);
      const int i1 = ((bf >> (s - 1)) << s) + jq;
      const int i2 = i1 + half;
      float ang = (PI2 / (float)(1 << s)) * (float)jq;
      float wr, wi;
      __sincosf(ang, &wi, &wr);
      float xr = re[i2][c], xi = im[i2][c];
      float pr = xr * wr - xi * wi;
      float pi = xr * wi + xi * wr;
      float ur = re[i1][c], ui = im[i1][c];
      re[i1][c] = ur + pr; im[i1][c] = ui + pi;
      re[i2][c] = ur - pr; im[i2][c] = ui - pi;
    }
  }
  __syncthreads();
  float2* base = T + (size_t)img * N * Wf + k0;
  for (int r = g; r < N; r += 16)
    if (act) base[(size_t)r * Wf + c] = make_float2(re[r][c], im[r][c]);
}

// row irfft: Hermitian-extend N/2+1 bins to N, inverse FFT, keep real*scale
template<int N, int LOG2N>
__global__ void irfft_rows(const float2* __restrict__ T, float* __restrict__ out, float scale) {
  __shared__ float re[N], im[N];
  const int row = blockIdx.x;
  const float2* p = T + (size_t)row * (N / 2 + 1);
  const int tid = threadIdx.x;  // N/2
  for (int i = tid; i < N; i += N / 2) {
    float2 v;
    if (i <= N / 2) v = p[i];
    else { v = p[N - i]; v.y = -v.y; }
    int j = __brev((unsigned)i) >> (32 - LOG2N);
    re[j] = v.x; im[j] = v.y;
  }
  fft_stages<N, LOG2N>(re, im, tid, 1.f);
  float* q = out + (size_t)row * N;
  for (int i = tid; i < N; i += N / 2) q[i] = re[i] * scale;
}

// ---------------- y_in = w_in(32x64) @ x[:, :64] + b_in (float4 pixels) ----------------
// software-pipelined: 4-channel groups, prefetch next group during FMA block
__global__ __launch_bounds__(256, 4) void conv_in_v(const float* __restrict__ x,
                          const float* __restrict__ w,
                          const float* __restrict__ bias, float* __restrict__ y) {
  __shared__ float wt[32 * 64];  // wt[ci*32+o]
  __shared__ float bl[32];
  const int t = threadIdx.x;
  for (int idx = t; idx < 2048; idx += 256) wt[idx] = w[(idx & 31) * 64 + (idx >> 5)];
  if (t < 32) bl[t] = bias[t];
  __syncthreads();
  const int og = t >> 6;                       // 0..3 -> outputs og*8..og*8+7 (wave-uniform)
  const int p4 = blockIdx.x * 64 + (t & 63);   // 65536 float4-pixels
  const int hw4 = p4 & 16383;
  const int b = p4 >> 14;
  const float4* xb = (const float4*)x + (size_t)b * 128 * 16384 + hw4;
  float4 acc[8];
#pragma unroll
  for (int o = 0; o < 8; ++o) { float bv = bl[og * 8 + o]; acc[o] = make_float4(bv, bv, bv, bv); }
  float4 n0 = xb[0], n1 = xb[16384], n2 = xb[2 * 16384], n3 = xb[3 * 16384];
  for (int ci = 0; ci < 64; ci += 4) {
    float4 c0 = n0, c1 = n1, c2 = n2, c3 = n3;
    if (ci < 60) {
      const float4* np = xb + (size_t)(ci + 4) * 16384;
      n0 = np[0]; n1 = np[16384]; n2 = np[2 * 16384]; n3 = np[3 * 16384];
    }
#pragma unroll
    for (int k = 0; k < 4; ++k) {
      float4 v = (k == 0) ? c0 : (k == 1) ? c1 : (k == 2) ? c2 : c3;
      const float4* w4p = (const float4*)&wt[(ci + k) * 32 + og * 8];
      float4 a = w4p[0], c = w4p[1];
      fma4(acc[0], a.x, v); fma4(acc[1], a.y, v); fma4(acc[2], a.z, v); fma4(acc[3], a.w, v);
      fma4(acc[4], c.x, v); fma4(acc[5], c.y, v); fma4(acc[6], c.z, v); fma4(acc[7], c.w, v);
    }
  }
  float4* yb = (float4*)y + (size_t)(b * 32 + og * 8) * 16384 + hw4;
#pragma unroll
  for (int o = 0; o < 8; ++o) yb[(size_t)o * 16384] = acc[o];
}

// ---------------- spectral conv: pairs of complex pixels (float4 loads) ----------------
// software-pipelined: prefetch next channel's pair during FMA block
template<int B_, int H_, int Wf_>
__global__ __launch_bounds__(256, 4) void conv_spec_v(const float4* __restrict__ S4,
                            const float* __restrict__ w,
                            const float* __restrict__ bias, float2* __restrict__ Z2) {
  constexpr int PP = H_ * Wf_ / 2;      // complex pairs per (b,ci) plane
  constexpr int CHS2 = B_ * PP;         // pairs per out-channel
  __shared__ float wt[64 * 64];         // wt[ci*64+co]
  __shared__ float bl[64];
  const int t = threadIdx.x;
  for (int idx = t; idx < 4096; idx += 256) wt[idx] = w[(idx & 63) * 64 + (idx >> 6)];
  if (t < 64) bl[t] = bias[t];
  __syncthreads();
  const int og = t >> 7;                        // 0/1 -> 32 outputs (wave-uniform)
  const int j2 = blockIdx.x * 128 + (t & 127);  // global pair index
  const int b = j2 / PP;
  const int jp = j2 - b * PP;
  float2 acc[32];
#pragma unroll
  for (int o = 0; o < 32; ++o) { float bv = bl[og * 32 + o]; acc[o] = make_float2(bv, bv); }
  const float4* sp = S4 + (size_t)(b * 32) * PP + jp;
  float4 nv = sp[0];
  for (int ci = 0; ci < 32; ++ci) {
    float4 sv = nv;                      // two complex: (x,y) (z,w)
    if (ci < 31) nv = sp[(size_t)(ci + 1) * PP];
    const float4* wr4 = (const float4*)&wt[ci * 64 + og * 32];
    const float4* wi4 = (const float4*)&wt[(ci + 32) * 64 + og * 32];
#pragma unroll
    for (int o4 = 0; o4 < 8; ++o4) {
      float4 a = wr4[o4], c = wi4[o4];
      acc[4 * o4 + 0].x += a.x * sv.x + c.x * sv.y;  acc[4 * o4 + 0].y += a.x * sv.z + c.x * sv.w;
      acc[4 * o4 + 1].x += a.y * sv.x + c.y * sv.y;  acc[4 * o4 + 1].y += a.y * sv.z + c.y * sv.w;
      acc[4 * o4 + 2].x += a.z * sv.x + c.z * sv.y;  acc[4 * o4 + 2].y += a.z * sv.z + c.z * sv.w;
      acc[4 * o4 + 3].x += a.w * sv.x + c.w * sv.y;  acc[4 * o4 + 3].y += a.w * sv.z + c.w * sv.w;
    }
  }
#pragma unroll
  for (int o = 0; o < 32; ++o) Z2[(size_t)(og * 32 + o) * CHS2 + j2] = acc[o];
}

// ---------------- BN stats: stage 1 (64 channels x 32 slices), stage 2 finalize ----------------
__global__ void bn_stats_part(const float* __restrict__ Z, int chunk, double* __restrict__ pb) {
  const int c = blockIdx.x >> 5;
  const int sl = blockIdx.x & 31;
  const float* p = Z + (size_t)c * ((size_t)chunk * 32) + (size_t)sl * chunk;
  double s = 0.0, s2 = 0.0;
  for (int i = threadIdx.x; i < chunk; i += 256) {
    float v = p[i];
    s += v;
    s2 += (double)v * (double)v;
  }
  __shared__ double sh[256], sh2[256];
  sh[threadIdx.x] = s; sh2[threadIdx.x] = s2;
  __syncthreads();
  for (int off = 128; off > 0; off >>= 1) {
    if (threadIdx.x < off) { sh[threadIdx.x] += sh[threadIdx.x + off]; sh2[threadIdx.x] += sh2[threadIdx.x + off]; }
    __syncthreads();
  }
  if (threadIdx.x == 0) { pb[2 * blockIdx.x] = sh[0]; pb[2 * blockIdx.x + 1] = sh2[0]; }
}

__global__ void bn_finalize(const double* __restrict__ pb, int n,
                            const float* __restrict__ gamma, const float* __restrict__ beta,
                            float* __restrict__ scale, float* __restrict__ shift) {
  const int c = threadIdx.x;  // 64 threads
  double s = 0.0, s2 = 0.0;
  for (int i = 0; i < 32; ++i) { s += pb[2 * (c * 32 + i)]; s2 += pb[2 * (c * 32 + i) + 1]; }
  double mu = s / (double)n;
  double var = s2 / (double)n - mu * mu;
  float rs = (float)(1.0 / sqrt(var + 1e-5));
  float g = gamma[c] * rs;
  scale[c] = g;
  shift[c] = beta[c] - (float)mu * g;
}

// ---------------- epilogues: 256 threads, 4 og x 8 outputs, 2 px/thread, out split x2 -------
// Design point from R1/R3/R4 matrix: need LDS ratio (4 b128 : 128 fmac per ci) AND >=16
// waves/CU. ohalf splits the 64 outputs across 2 blocks -> grid 1024 = 4 blocks/CU,
// LDS 16.5/12.4 KB, VGPR ~110 under cap 128. Accumulation order bit-identical.
__global__ __launch_bounds__(256, 4) void final_l_v(const float* __restrict__ x,
                          const float* __restrict__ w_local, const float* __restrict__ b_local,
                          const float* __restrict__ w_g2l, const float* __restrict__ b_g2l,
                          float* __restrict__ out) {
  __shared__ float wg[64 * 32], wl[64 * 32], bb[32];
  const int t = threadIdx.x;
  const int ohalf = blockIdx.x & 1;
  const int pblk = blockIdx.x >> 1;
  for (int idx = t; idx < 2048; idx += 256) {
    int oo = idx & 31, ci = idx >> 5;
    wg[idx] = w_g2l[(ohalf * 32 + oo) * 64 + ci];
    wl[idx] = w_local[(ohalf * 32 + oo) * 64 + ci];
  }
  if (t < 32) bb[t] = b_local[ohalf * 32 + t] + b_g2l[ohalf * 32 + t];
  __syncthreads();
  const int og = t >> 6;                        // 0..3 -> 8 outputs each
  const int lane = t & 63;
  const int p4 = pblk * 128 + lane;             // pixel a; pixel b = +64
  const int hw4 = p4 & 16383;
  const int b = p4 >> 14;
  const float4* xb = (const float4*)x + (size_t)b * 128 * 16384 + hw4;
  float4 acc0[8], acc1[8];
#pragma unroll
  for (int o = 0; o < 8; ++o) {
    float bv = bb[og * 8 + o];
    acc0[o] = make_float4(bv, bv, bv, bv);
    acc1[o] = make_float4(bv, bv, bv, bv);
  }
  float4 nga = xb[0], ngb = xb[64];
  float4 nla = xb[(size_t)64 * 16384], nlb = xb[(size_t)64 * 16384 + 64];
  for (int ci = 0; ci < 64; ++ci) {
    float4 ga = nga, gb2 = ngb, la = nla, lb2 = nlb;
    if (ci < 63) {
      const float4* np = xb + (size_t)(ci + 1) * 16384;
      nga = np[0]; ngb = np[64];
      nla = np[(size_t)64 * 16384]; nlb = np[(size_t)64 * 16384 + 64];
    }
    const float4* g4 = (const float4*)&wg[ci * 32 + og * 8];
    const float4* l4 = (const float4*)&wl[ci * 32 + og * 8];
    float4 a0 = g4[0], a1 = g4[1];
    float4 c0 = l4[0], c1 = l4[1];
    fma4(acc0[0], a0.x, ga); fma4(acc0[0], c0.x, la);
    fma4(acc1[0], a0.x, gb2); fma4(acc1[0], c0.x, lb2);
    fma4(acc0[1], a0.y, ga); fma4(acc0[1], c0.y, la);
    fma4(acc1[1], a0.y, gb2); fma4(acc1[1], c0.y, lb2);
    fma4(acc0[2], a0.z, ga); fma4(acc0[2], c0.z, la);
    fma4(acc1[2], a0.z, gb2); fma4(acc1[2], c0.z, lb2);
    fma4(acc0[3], a0.w, ga); fma4(acc0[3], c0.w, la);
    fma4(acc1[3], a0.w, gb2); fma4(acc1[3], c0.w, lb2);
    fma4(acc0[4], a1.x, ga); fma4(acc0[4], c1.x, la);
    fma4(acc1[4], a1.x, gb2); fma4(acc1[4], c1.x, lb2);
    fma4(acc0[5], a1.y, ga); fma4(acc0[5], c1.y, la);
    fma4(acc1[5], a1.y, gb2); fma4(acc1[5], c1.y, lb2);
    fma4(acc0[6], a1.z, ga); fma4(acc0[6], c1.z, la);
    fma4(acc1[6], a1.z, gb2); fma4(acc1[6], c1.z, lb2);
    fma4(acc0[7], a1.w, ga); fma4(acc0[7], c1.w, la);
    fma4(acc1[7], a1.w, gb2); fma4(acc1[7], c1.w, lb2);
  }
  float4* ob = (float4*)out + (size_t)(b * 128 + 64 + ohalf * 32 + og * 8) * 16384 + hw4;
#pragma unroll
  for (int o = 0; o < 8; ++o) {
    ob[(size_t)o * 16384] = acc0[o];
    ob[(size_t)o * 16384 + 64] = acc1[o];
  }
}

__global__ __launch_bounds__(256, 4) void final_g_v(const float* __restrict__ x,
                          const float* __restrict__ y_g, const float* __restrict__ y2,
                          const float* __restrict__ w_out, const float* __restrict__ b_out,
                          const float* __restrict__ w_l2g, const float* __restrict__ b_l2g,
                          float* __restrict__ out) {
  __shared__ float wo[32 * 32], wl[64 * 32], bb[32];
  const int t = threadIdx.x;
  const int ohalf = blockIdx.x & 1;
  const int pblk = blockIdx.x >> 1;
  for (int idx = t; idx < 1024; idx += 256) {
    int oo = idx & 31, ci = idx >> 5;
    wo[idx] = w_out[(ohalf * 32 + oo) * 32 + ci];
  }
  for (int idx = t; idx < 2048; idx += 256) {
    int oo = idx & 31, ci = idx >> 5;
    wl[idx] = w_l2g[(ohalf * 32 + oo) * 64 + ci];
  }
  if (t < 32) bb[t] = b_out[ohalf * 32 + t] + b_l2g[ohalf * 32 + t];
  __syncthreads();
  const int og = t >> 6;                        // 0..3 -> 8 outputs each
  const int lane = t & 63;
  const int p4 = pblk * 128 + lane;             // pixel a; pixel b = +64
  const int hw4 = p4 & 16383;
  const int b = p4 >> 14;
  const int ha = hw4 >> 6;                      // 64 float4 per row; lanes cover one row
  const int wa = hw4 & 63;
  const int hw2a = ((ha & 127) << 5) + (wa & 31);
  const int hw2b = (((ha + 1) & 127) << 5) + (wa & 31);   // pixel b is next row
  const float4* xb = (const float4*)x + (size_t)(b * 128 + 64) * 16384 + hw4;
  const float4* gb = (const float4*)y_g + (size_t)b * 32 * 16384 + hw4;
  const float4* ta = (const float4*)y2 + (size_t)b * 32 * 4096 + hw2a;
  const float4* tb = (const float4*)y2 + (size_t)b * 32 * 4096 + hw2b;
  float4 acc0[8], acc1[8];
#pragma unroll
  for (int o = 0; o < 8; ++o) {
    float bv = bb[og * 8 + o];
    acc0[o] = make_float4(bv, bv, bv, bv);
    acc1[o] = make_float4(bv, bv, bv, bv);
  }
  // ---- pass 1: s = y_g + y2 (32 channels), 1-ch prefetch ----
  float4 npga = gb[0], npgb = gb[64];
  float4 npta = ta[0], nptb = tb[0];
  for (int ci = 0; ci < 32; ++ci) {
    float4 sa = add4(npga, npta), sb = add4(npgb, nptb);
    if (ci < 31) {
      npga = gb[(size_t)(ci + 1) * 16384]; npgb = gb[(size_t)(ci + 1) * 16384 + 64];
      npta = ta[(size_t)(ci + 1) * 4096];  nptb = tb[(size_t)(ci + 1) * 4096];
    }
    const float4* w4p = (const float4*)&wo[ci * 32 + og * 8];
    float4 a0 = w4p[0], a1 = w4p[1];
    fma4(acc0[0], a0.x, sa); fma4(acc1[0], a0.x, sb);
    fma4(acc0[1], a0.y, sa); fma4(acc1[1], a0.y, sb);
    fma4(acc0[2], a0.z, sa); fma4(acc1[2], a0.z, sb);
    fma4(acc0[3], a0.w, sa); fma4(acc1[3], a0.w, sb);
    fma4(acc0[4], a1.x, sa); fma4(acc1[4], a1.x, sb);
    fma4(acc0[5], a1.y, sa); fma4(acc1[5], a1.y, sb);
    fma4(acc0[6], a1.z, sa); fma4(acc1[6], a1.z, sb);
    fma4(acc0[7], a1.w, sa); fma4(acc1[7], a1.w, sb);
  }
  // ---- pass 2: x_l (64 channels), 1-ch prefetch ----
  float4 nxa = xb[0], nxb = xb[64];
  for (int ci = 0; ci < 64; ++ci) {
    float4 xa = nxa, xb2 = nxb;
    if (ci < 63) {
      nxa = xb[(size_t)(ci + 1) * 16384];
      nxb = xb[(size_t)(ci + 1) * 16384 + 64];
    }
    const float4* w4p = (const float4*)&wl[ci * 32 + og * 8];
    float4 a0 = w4p[0], a1 = w4p[1];
    fma4(acc0[0], a0.x, xa); fma4(acc1[0], a0.x, xb2);
    fma4(acc0[1], a0.y, xa); fma4(acc1[1], a0.y, xb2);
    fma4(acc0[2], a0.z, xa); fma4(acc1[2], a0.z, xb2);
    fma4(acc0[3], a0.w, xa); fma4(acc1[3], a0.w, xb2);
    fma4(acc0[4], a1.x, xa); fma4(acc1[4], a1.x, xb2);
    fma4(acc0[5], a1.y, xa); fma4(acc1[5], a1.y, xb2);
    fma4(acc0[6], a1.z, xa); fma4(acc1[6], a1.z, xb2);
    fma4(acc0[7], a1.w, xa); fma4(acc1[7], a1.w, xb2);
  }
  float4* ob = (float4*)out + (size_t)(b * 128 + ohalf * 32 + og * 8) * 16384 + hw4;
#pragma unroll
  for (int o = 0; o < 8; ++o) {
    ob[(size_t)o * 16384] = acc0[o];
    ob[(size_t)o * 16384 + 64] = acc1[o];
  }
}

extern "C" void kernel_launch(void* const* d_in, const int* in_sizes, int n_in,
                              void* d_out, int out_size, void* d_ws, size_t ws_size,
                              hipStream_t stream) {
  (void)in_sizes; (void)n_in; (void)out_size; (void)ws_size;
  const float* x       = (const float*)d_in[0];
  const float* w_local = (const float*)d_in[1];
  const float* b_local = (const float*)d_in[2];
  const float* w_in    = (const float*)d_in[3];
  const float* b_in    = (const float*)d_in[4];
  const float* w_out   = (const float*)d_in[5];
  const float* b_out   = (const float*)d_in[6];
  const float* w_g2l   = (const float*)d_in[7];
  const float* b_g2l   = (const float*)d_in[8];
  const float* w_l2g   = (const float*)d_in[9];
  const float* b_l2g   = (const float*)d_in[10];
  const float* w_fu1   = (const float*)d_in[11];
  const float* b_fu1   = (const float*)d_in[12];
  const float* g_fu1   = (const float*)d_in[13];
  const float* be_fu1  = (const float*)d_in[14];
  const float* w_fu2   = (const float*)d_in[15];
  const float* b_fu2   = (const float*)d_in[16];
  const float* g_fu2   = (const float*)d_in[17];
  const float* be_fu2  = (const float*)d_in[18];
  float* out = (float*)d_out;

  // workspace layout (floats)
  float* ws   = (float*)d_ws;
  float* y_in = ws;                       // 8,388,608
  float* S1   = y_in + 8388608;           // 8,454,144 floats (spectral FU1; dead during bn_stats1)
  float* Z1   = S1 + 8454144;             // 8,454,144 (y_g overlays after Z1 dead)
  float* y_g  = Z1;
  float* S2   = Z1 + 8454144;             // 2,129,920 floats
  float* Z2   = S2 + 2129920;             // 2,129,920 (y2 overlays)
  float* y2   = Z2;
  float* st1  = Z2 + 2129920;             // scale[64], shift[64]
  float* st2  = st1 + 128;
  double* pb1 = (double*)S1;              // 64*32*2 doubles, overlaid on dead S1
  double* pb2 = (double*)S2;

  conv_in_v<<<1024, 256, 0, stream>>>(x, w_in, b_in, y_in);

  // ---- FU1 (256x256, Wf=129) ----
  rfft_rows<256, 8><<<32768, 128, 0, stream>>>(y_in, (float2*)S1);
  cfft_cols_t<256, 8, 16><<<128 * 9, 256, 0, stream>>>((float2*)S1, 129, -1.f, 9);
  conv_spec_v<4, 256, 129><<<516, 256, 0, stream>>>((const float4*)S1, w_fu1, b_fu1, (float2*)Z1);
  bn_stats_part<<<2048, 256, 0, stream>>>(Z1, 4128, pb1);
  bn_finalize<<<1, 64, 0, stream>>>(pb1, 132096, g_fu1, be_fu1, st1, st1 + 64);
  cfft_inv_bn<256, 8, 16><<<128 * 9, 256, 0, stream>>>(Z1, st1, st1 + 64, (float2*)S1, 129, 9, 132096);
  irfft_rows<256, 8><<<32768, 128, 0, stream>>>((const float2*)S1, y_g, 1.f / 65536.f);

  // ---- FU2 / LFU (128x128, Wf=65) ----
  rfft_rows_lfu<<<16384, 64, 0, stream>>>(y_in, (float2*)S2);
  cfft_cols_t<128, 7, 16><<<128 * 5, 256, 0, stream>>>((float2*)S2, 65, -1.f, 5);
  conv_spec_v<4, 128, 65><<<130, 256, 0, stream>>>((const float4*)S2, w_fu2, b_fu2, (float2*)Z2);
  bn_stats_part<<<2048, 256, 0, stream>>>(Z2, 1040, pb2);
  bn_finalize<<<1, 64, 0, stream>>>(pb2, 33280, g_fu2, be_fu2, st2, st2 + 64);
  cfft_inv_bn<128, 7, 16><<<128 * 5, 256, 0, stream>>>(Z2, st2, st2 + 64, (float2*)S2, 65, 5, 33280);
  irfft_rows<128, 7><<<16384, 64, 0, stream>>>((const float2*)S2, y2, 1.f / 16384.f);

  // ---- epilogues ----
  final_g_v<<<1024, 256, 0, stream>>>(x, y_g, y2, w_out, b_out, w_l2g, b_l2g, out);
  final_l_v<<<1024, 256, 0, stream>>>(x, w_local, b_local, w_g2l, b_g2l, out);
}

// Round 6
// 608.997 us; speedup vs baseline: 1.6807x; 1.6807x over previous
//
#include <hip/hip_runtime.h>
#include <math.h>

// FastFourierConvolution: B=4, C=128, H=W=256. Cg=Cl=64, Ci=32.
// FU1: (B,32,256,256) -> rfft2 -> conv64x64+BN+relu -> herm irfft2
// FU2 (LFU): y_in[:,24:32] quadrant-stacked to (B,32,128,128), same pipeline, tiled 2x2.
// R6: all kernels restored to the R1-proven forms; independent dispatches fused
// (final_g+final_l, conv_spec FU1+FU2, bn_stats x2, bn_finalize x2) for occupancy
// and launch-gap savings. Math and accumulation order bit-identical to R1.

#define PI2 6.283185307179586f

__device__ __forceinline__ void fma4(float4& a, float w, const float4& v) {
  a.x += w * v.x; a.y += w * v.y; a.z += w * v.z; a.w += w * v.w;
}
__device__ __forceinline__ float4 add4(const float4& a, const float4& b) {
  return make_float4(a.x + b.x, a.y + b.y, a.z + b.z, a.w + b.w);
}

// ---------------- FFT core: radix-2 DIT in LDS, blockDim == N/2 ----------------
template<int N, int LOG2N>
__device__ __forceinline__ void fft_stages(float* re, float* im, int tid, float sign) {
#pragma unroll
  for (int s = 1; s <= LOG2N; ++s) {
    __syncthreads();
    const int half = 1 << (s - 1);
    const int j = tid & (half - 1);
    const int i1 = ((tid >> (s - 1)) << s) + j;
    const int i2 = i1 + half;
    float ang = sign * (PI2 / (float)(1 << s)) * (float)j;
    float wr, wi;
    __sincosf(ang, &wi, &wr);
    float xr = re[i2], xi = im[i2];
    float vr = xr * wr - xi * wi;
    float vi = xr * wi + xi * wr;
    float ur = re[i1], ui = im[i1];
    re[i1] = ur + vr; im[i1] = ui + vi;
    re[i2] = ur - vr; im[i2] = ui - vi;
  }
  __syncthreads();
}

// row rfft: one block per row of length N (real) -> N/2+1 complex bins
template<int N, int LOG2N>
__global__ void rfft_rows(const float* __restrict__ src, float2* __restrict__ dst) {
  __shared__ float re[N], im[N];
  const int row = blockIdx.x;
  const int tid = threadIdx.x;  // N/2 threads
  const float* p = src + (size_t)row * N;
  for (int i = tid; i < N; i += N / 2) {
    int j = __brev((unsigned)i) >> (32 - LOG2N);
    re[j] = p[i];
    im[j] = 0.f;
  }
  fft_stages<N, LOG2N>(re, im, tid, -1.f);
  float2* q = dst + (size_t)row * (N / 2 + 1);
  for (int k = tid; k <= N / 2; k += N / 2) q[k] = make_float2(re[k], im[k]);
}

// LFU gather + row rfft (N=128): reads quadrants of y_in channels 24..31
__global__ void rfft_rows_lfu(const float* __restrict__ y_in, float2* __restrict__ dst) {
  __shared__ float re[128], im[128];
  const int bid = blockIdx.x;          // ((b*32+c2)*128 + h2)
  const int h2 = bid & 127;
  const int c2 = (bid >> 7) & 31;
  const int b  = bid >> 12;
  const int q = c2 >> 3, ch = c2 & 7;
  const int hs = ((q >> 1) << 7) + h2;
  const int ws0 = (q & 1) << 7;
  const float* p = y_in + (((size_t)(b * 32 + 24 + ch) * 256 + hs) * 256 + ws0);
  const int tid = threadIdx.x;  // 64
  for (int i = tid; i < 128; i += 64) {
    int j = __brev((unsigned)i) >> 25;
    re[j] = p[i];
    im[j] = 0.f;
  }
  fft_stages<128, 7>(re, im, tid, -1.f);
  float2* qp = dst + (size_t)bid * 65;
  for (int k = tid; k <= 64; k += 64) qp[k] = make_float2(re[k], im[k]);
}

// ---------------- tiled forward column FFT: block = 16 columns x N rows ----------------
template<int N, int LOG2N, int TW>
__global__ void cfft_cols_t(float2* __restrict__ data, int Wf, float sign, int tilesPerImg) {
  __shared__ float re[N][TW + 1], im[N][TW + 1];
  const int img = blockIdx.x / tilesPerImg;
  const int k0 = (blockIdx.x % tilesPerImg) * TW;
  const int cols = min(TW, Wf - k0);
  float2* base = data + (size_t)img * N * Wf + k0;
  const int t = threadIdx.x;
  const int c = t & (TW - 1);
  const int g = t >> 4;
  const bool act = (c < cols);
  for (int r = g; r < N; r += 16) {
    float2 v;
    if (act) v = base[(size_t)r * Wf + c];
    int j = __brev((unsigned)r) >> (32 - LOG2N);
    if (act) { re[j][c] = v.x; im[j][c] = v.y; }
  }
#pragma unroll
  for (int s = 1; s <= LOG2N; ++s) {
    __syncthreads();
    const int half = 1 << (s - 1);
    for (int bf = g; bf < N / 2; bf += 16) {
      if (!act) continue;
      const int j = bf & (half - 1);
      const int i1 = ((bf >> (s - 1)) << s) + j;
      const int i2 = i1 + half;
      float ang = sign * (PI2 / (float)(1 << s)) * (float)j;
      float wr, wi;
      __sincosf(ang, &wi, &wr);
      float xr = re[i2][c], xi = im[i2][c];
      float vr = xr * wr - xi * wi;
      float vi = xr * wi + xi * wr;
      float ur = re[i1][c], ui = im[i1][c];
      re[i1][c] = ur + vr; im[i1][c] = ui + vi;
      re[i2][c] = ur - vr; im[i2][c] = ui - vi;
    }
  }
  __syncthreads();
  for (int r = g; r < N; r += 16) {
    if (act) base[(size_t)r * Wf + c] = make_float2(re[r][c], im[r][c]);
  }
}

// ---------------- fused BN+relu+symmetrize + inverse column FFT ----------------
template<int N, int LOG2N, int TW>
__global__ void cfft_inv_bn(const float* __restrict__ Z, const float* __restrict__ scale,
                            const float* __restrict__ shift, float2* __restrict__ T,
                            int Wf, int tilesPerImg, int chs) {
  __shared__ float re[N][TW + 1], im[N][TW + 1];
  const int img = blockIdx.x / tilesPerImg;    // b*32 + cc
  const int b = img >> 5, cc = img & 31;
  const int k0 = (blockIdx.x % tilesPerImg) * TW;
  const int cols = min(TW, Wf - k0);
  const int t = threadIdx.x;
  const int c = t & (TW - 1);
  const int g = t >> 4;
  const bool act = (c < cols);
  const int kk = k0 + c;
  const float scr = scale[cc], sfr = shift[cc];
  const float sci = scale[cc + 32], sfi = shift[cc + 32];
  const float* Zr = Z + (size_t)cc * chs + (size_t)b * N * Wf;
  const float* Zi = Z + (size_t)(cc + 32) * chs + (size_t)b * N * Wf;
  const bool edge = (kk == 0 || kk == Wf - 1);
  for (int r = g; r < N; r += 16) {
    float vr = 0.f, vi = 0.f;
    if (act) {
      size_t p = (size_t)r * Wf + kk;
      float yr = fmaxf(Zr[p] * scr + sfr, 0.f);
      float yi = fmaxf(Zi[p] * sci + sfi, 0.f);
      if (edge) {
        int rm = (N - r) & (N - 1);
        size_t pm = (size_t)rm * Wf + kk;
        float yr2 = fmaxf(Zr[pm] * scr + sfr, 0.f);
        float yi2 = fmaxf(Zi[pm] * sci + sfi, 0.f);
        yr = 0.5f * (yr + yr2);
        yi = 0.5f * (yi - yi2);
      }
      vr = yr; vi = yi;
    }
    int j = __brev((unsigned)r) >> (32 - LOG2N);
    if (act) { re[j][c] = vr; im[j][c] = vi; }
  }
#pragma unroll
  for (int s = 1; s <= LOG2N; ++s) {
    __syncthreads();
    const int half = 1 << (s - 1);
    for (int bf = g; bf < N / 2; bf += 16) {
      if (!act) continue;
      const int jq = bf & (half - 1);
      const int i1 = ((bf >> (s - 1)) << s) + jq;
      const int i2 = i1 + half;
      float ang = (PI2 / (float)(1 << s)) * (float)jq;
      float wr, wi;
      __sincosf(ang, &wi, &wr);
      float xr = re[i2][c], xi = im[i2][c];
      float pr = xr * wr - xi * wi;
      float pi = xr * wi + xi * wr;
      float ur = re[i1][c], ui = im[i1][c];
      re[i1][c] = ur + pr; im[i1][c] = ui + pi;
      re[i2][c] = ur - pr; im[i2][c] = ui - pi;
    }
  }
  __syncthreads();
  float2* base = T + (size_t)img * N * Wf + k0;
  for (int r = g; r < N; r += 16)
    if (act) base[(size_t)r * Wf + c] = make_float2(re[r][c], im[r][c]);
}

// row irfft: Hermitian-extend N/2+1 bins to N, inverse FFT, keep real*scale
template<int N, int LOG2N>
__global__ void irfft_rows(const float2* __restrict__ T, float* __restrict__ out, float scale) {
  __shared__ float re[N], im[N];
  const int row = blockIdx.x;
  const float2* p = T + (size_t)row * (N / 2 + 1);
  const int tid = threadIdx.x;  // N/2
  for (int i = tid; i < N; i += N / 2) {
    float2 v;
    if (i <= N / 2) v = p[i];
    else { v = p[N - i]; v.y = -v.y; }
    int j = __brev((unsigned)i) >> (32 - LOG2N);
    re[j] = v.x; im[j] = v.y;
  }
  fft_stages<N, LOG2N>(re, im, tid, 1.f);
  float* q = out + (size_t)row * N;
  for (int i = tid; i < N; i += N / 2) q[i] = re[i] * scale;
}

// ---------------- y_in = w_in(32x64) @ x[:, :64] + b_in (R1-proven) ----------------
__global__ __launch_bounds__(256, 4) void conv_in_v(const float* __restrict__ x,
                          const float* __restrict__ w,
                          const float* __restrict__ bias, float* __restrict__ y) {
  __shared__ float wt[32 * 64];  // wt[ci*32+o]
  __shared__ float bl[32];
  const int t = threadIdx.x;
  for (int idx = t; idx < 2048; idx += 256) wt[idx] = w[(idx & 31) * 64 + (idx >> 5)];
  if (t < 32) bl[t] = bias[t];
  __syncthreads();
  const int og = t >> 6;                       // 0..3 -> outputs og*8..og*8+7 (wave-uniform)
  const int p4 = blockIdx.x * 64 + (t & 63);   // 65536 float4-pixels
  const int hw4 = p4 & 16383;
  const int b = p4 >> 14;
  const float4* xb = (const float4*)x + (size_t)b * 128 * 16384 + hw4;
  float4 acc[8];
#pragma unroll
  for (int o = 0; o < 8; ++o) { float bv = bl[og * 8 + o]; acc[o] = make_float4(bv, bv, bv, bv); }
  float4 n0 = xb[0], n1 = xb[16384], n2 = xb[2 * 16384], n3 = xb[3 * 16384];
  for (int ci = 0; ci < 64; ci += 4) {
    float4 c0 = n0, c1 = n1, c2 = n2, c3 = n3;
    if (ci < 60) {
      const float4* np = xb + (size_t)(ci + 4) * 16384;
      n0 = np[0]; n1 = np[16384]; n2 = np[2 * 16384]; n3 = np[3 * 16384];
    }
#pragma unroll
    for (int k = 0; k < 4; ++k) {
      float4 v = (k == 0) ? c0 : (k == 1) ? c1 : (k == 2) ? c2 : c3;
      const float4* w4p = (const float4*)&wt[(ci + k) * 32 + og * 8];
      float4 a = w4p[0], c = w4p[1];
      fma4(acc[0], a.x, v); fma4(acc[1], a.y, v); fma4(acc[2], a.z, v); fma4(acc[3], a.w, v);
      fma4(acc[4], c.x, v); fma4(acc[5], c.y, v); fma4(acc[6], c.z, v); fma4(acc[7], c.w, v);
    }
  }
  float4* yb = (float4*)y + (size_t)(b * 32 + og * 8) * 16384 + hw4;
#pragma unroll
  for (int o = 0; o < 8; ++o) yb[(size_t)o * 16384] = acc[o];
}

// ---------------- spectral conv body (R1-proven), fused FU1+FU2 dispatch ----------------
template<int B_, int H_, int Wf_>
__device__ __forceinline__ void conv_spec_body(const float4* __restrict__ S4,
                            const float* __restrict__ w, const float* __restrict__ bias,
                            float2* __restrict__ Z2, int bid, float* wt, float* bl) {
  constexpr int PP = H_ * Wf_ / 2;      // complex pairs per (b,ci) plane
  constexpr int CHS2 = B_ * PP;         // pairs per out-channel
  const int t = threadIdx.x;
  for (int idx = t; idx < 4096; idx += 256) wt[idx] = w[(idx & 63) * 64 + (idx >> 6)];
  if (t < 64) bl[t] = bias[t];
  __syncthreads();
  const int og = t >> 7;                        // 0/1 -> 32 outputs (wave-uniform)
  const int j2 = bid * 128 + (t & 127);         // global pair index
  const int b = j2 / PP;
  const int jp = j2 - b * PP;
  float2 acc[32];
#pragma unroll
  for (int o = 0; o < 32; ++o) { float bv = bl[og * 32 + o]; acc[o] = make_float2(bv, bv); }
  const float4* sp = S4 + (size_t)(b * 32) * PP + jp;
  float4 nv = sp[0];
  for (int ci = 0; ci < 32; ++ci) {
    float4 sv = nv;                      // two complex: (x,y) (z,w)
    if (ci < 31) nv = sp[(size_t)(ci + 1) * PP];
    const float4* wr4 = (const float4*)&wt[ci * 64 + og * 32];
    const float4* wi4 = (const float4*)&wt[(ci + 32) * 64 + og * 32];
#pragma unroll
    for (int o4 = 0; o4 < 8; ++o4) {
      float4 a = wr4[o4], c = wi4[o4];
      acc[4 * o4 + 0].x += a.x * sv.x + c.x * sv.y;  acc[4 * o4 + 0].y += a.x * sv.z + c.x * sv.w;
      acc[4 * o4 + 1].x += a.y * sv.x + c.y * sv.y;  acc[4 * o4 + 1].y += a.y * sv.z + c.y * sv.w;
      acc[4 * o4 + 2].x += a.z * sv.x + c.z * sv.y;  acc[4 * o4 + 2].y += a.z * sv.z + c.z * sv.w;
      acc[4 * o4 + 3].x += a.w * sv.x + c.w * sv.y;  acc[4 * o4 + 3].y += a.w * sv.z + c.w * sv.w;
    }
  }
#pragma unroll
  for (int o = 0; o < 32; ++o) Z2[(size_t)(og * 32 + o) * CHS2 + j2] = acc[o];
}

__global__ __launch_bounds__(256, 4) void conv_spec_fused(
    const float4* __restrict__ S1, const float* __restrict__ w1, const float* __restrict__ b1,
    float2* __restrict__ Z1,
    const float4* __restrict__ S2, const float* __restrict__ w2, const float* __restrict__ b2,
    float2* __restrict__ Z2) {
  __shared__ float wt[4096];
  __shared__ float bl[64];
  if (blockIdx.x < 516)
    conv_spec_body<4, 256, 129>(S1, w1, b1, Z1, blockIdx.x, wt, bl);
  else
    conv_spec_body<4, 128, 65>(S2, w2, b2, Z2, blockIdx.x - 516, wt, bl);
}

// ---------------- BN stats fused (FU1: 2048 blocks, FU2: 2048 blocks) ----------------
__global__ void bn_stats_fused(const float* __restrict__ Z1, const float* __restrict__ Z2,
                               double* __restrict__ pb1, double* __restrict__ pb2) {
  int bid = blockIdx.x;
  const float* Z; double* pb; int chunk;
  if (bid < 2048) { Z = Z1; pb = pb1; chunk = 4128; }
  else { bid -= 2048; Z = Z2; pb = pb2; chunk = 1040; }
  const int c = bid >> 5;
  const int sl = bid & 31;
  const float* p = Z + (size_t)c * ((size_t)chunk * 32) + (size_t)sl * chunk;
  double s = 0.0, s2 = 0.0;
  for (int i = threadIdx.x; i < chunk; i += 256) {
    float v = p[i];
    s += v;
    s2 += (double)v * (double)v;
  }
  __shared__ double sh[256], sh2[256];
  sh[threadIdx.x] = s; sh2[threadIdx.x] = s2;
  __syncthreads();
  for (int off = 128; off > 0; off >>= 1) {
    if (threadIdx.x < off) { sh[threadIdx.x] += sh[threadIdx.x + off]; sh2[threadIdx.x] += sh2[threadIdx.x + off]; }
    __syncthreads();
  }
  if (threadIdx.x == 0) { pb[2 * bid] = sh[0]; pb[2 * bid + 1] = sh2[0]; }
}

__global__ void bn_finalize_fused(const double* __restrict__ pb1, const double* __restrict__ pb2,
                                  const float* __restrict__ g1, const float* __restrict__ be1,
                                  const float* __restrict__ g2, const float* __restrict__ be2,
                                  float* __restrict__ st1, float* __restrict__ st2) {
  const int t = threadIdx.x;  // 128 threads: 0-63 FU1, 64-127 FU2
  const bool fu1 = (t < 64);
  const double* pb = fu1 ? pb1 : pb2;
  const int n = fu1 ? 132096 : 33280;
  const float* gamma = fu1 ? g1 : g2;
  const float* beta  = fu1 ? be1 : be2;
  float* scale = fu1 ? st1 : st2;
  float* shift = fu1 ? (st1 + 64) : (st2 + 64);
  const int c = t & 63;
  double s = 0.0, s2 = 0.0;
  for (int i = 0; i < 32; ++i) { s += pb[2 * (c * 32 + i)]; s2 += pb[2 * (c * 32 + i) + 1]; }
  double mu = s / (double)n;
  double var = s2 / (double)n - mu * mu;
  float rs = (float)(1.0 / sqrt(var + 1e-5));
  float g = gamma[c] * rs;
  scale[c] = g;
  shift[c] = beta[c] - (float)mu * g;
}

// ---------------- fused epilogue: R1-proven bodies, parity block-split ----------------
__device__ __forceinline__ void final_l_body(const float* __restrict__ x, float* __restrict__ out,
                                             const float* wg, const float* wl, const float* bb,
                                             int pblk, int t) {
  const int og = t >> 6;                       // 16 outputs
  const int p4 = pblk * 64 + (t & 63);
  const int hw4 = p4 & 16383;
  const int b = p4 >> 14;
  const float4* xb = (const float4*)x + (size_t)b * 128 * 16384 + hw4;
  float4 acc[16];
#pragma unroll
  for (int o = 0; o < 16; ++o) { float bv = bb[og * 16 + o]; acc[o] = make_float4(bv, bv, bv, bv); }
  float4 g0 = xb[0], g1 = xb[16384];
  float4 l0 = xb[(size_t)64 * 16384], l1 = xb[(size_t)65 * 16384];
  for (int ci = 0; ci < 64; ci += 2) {
    float4 cg0 = g0, cg1 = g1, cl0 = l0, cl1 = l1;
    if (ci < 62) {
      const float4* np = xb + (size_t)(ci + 2) * 16384;
      g0 = np[0]; g1 = np[16384];
      l0 = np[(size_t)64 * 16384]; l1 = np[(size_t)65 * 16384];
    }
#pragma unroll
    for (int k = 0; k < 2; ++k) {
      float4 xg = k ? cg1 : cg0;
      float4 xl = k ? cl1 : cl0;
      const float4* g4 = (const float4*)&wg[(ci + k) * 64 + og * 16];
      const float4* l4 = (const float4*)&wl[(ci + k) * 64 + og * 16];
#pragma unroll
      for (int o4 = 0; o4 < 4; ++o4) {
        float4 a = g4[o4], cw = l4[o4];
        fma4(acc[4 * o4 + 0], a.x, xg); fma4(acc[4 * o4 + 0], cw.x, xl);
        fma4(acc[4 * o4 + 1], a.y, xg); fma4(acc[4 * o4 + 1], cw.y, xl);
        fma4(acc[4 * o4 + 2], a.z, xg); fma4(acc[4 * o4 + 2], cw.z, xl);
        fma4(acc[4 * o4 + 3], a.w, xg); fma4(acc[4 * o4 + 3], cw.w, xl);
      }
    }
  }
  float4* ob = (float4*)out + (size_t)(b * 128 + 64 + og * 16) * 16384 + hw4;
#pragma unroll
  for (int o = 0; o < 16; ++o) ob[(size_t)o * 16384] = acc[o];
}

__device__ __forceinline__ void final_g_body(const float* __restrict__ x,
                                             const float* __restrict__ y_g, const float* __restrict__ y2,
                                             float* __restrict__ out,
                                             const float* wo, const float* wl, const float* bb,
                                             int pblk, int t) {
  const int og = t >> 6;                       // 16 outputs
  const int p4 = pblk * 64 + (t & 63);
  const int hw4 = p4 & 16383;
  const int b = p4 >> 14;
  const int h = hw4 >> 6;                      // 64 float4 per row
  const int w4 = hw4 & 63;
  const int hw2_4 = ((h & 127) << 5) + (w4 & 31);
  const float4* xb = (const float4*)x + (size_t)(b * 128 + 64) * 16384 + hw4;
  const float4* gb = (const float4*)y_g + (size_t)b * 32 * 16384 + hw4;
  const float4* tb = (const float4*)y2 + (size_t)b * 32 * 4096 + hw2_4;
  float4 acc[16];
#pragma unroll
  for (int o = 0; o < 16; ++o) { float bv = bb[og * 16 + o]; acc[o] = make_float4(bv, bv, bv, bv); }
  // ---- pass 1: s = y_g + y2 (32 channels), 2-channel groups with prefetch ----
  float4 pg0 = gb[0], pg1 = gb[16384];
  float4 pt0 = tb[0], pt1 = tb[4096];
  for (int ci = 0; ci < 32; ci += 2) {
    float4 s0 = add4(pg0, pt0), s1 = add4(pg1, pt1);
    if (ci < 30) {
      const float4* gp = gb + (size_t)(ci + 2) * 16384;
      const float4* tp = tb + (size_t)(ci + 2) * 4096;
      pg0 = gp[0]; pg1 = gp[16384];
      pt0 = tp[0]; pt1 = tp[4096];
    }
#pragma unroll
    for (int k = 0; k < 2; ++k) {
      float4 s = k ? s1 : s0;
      const float4* w4p = (const float4*)&wo[(ci + k) * 64 + og * 16];
#pragma unroll
      for (int o4 = 0; o4 < 4; ++o4) {
        float4 a = w4p[o4];
        fma4(acc[4 * o4 + 0], a.x, s);
        fma4(acc[4 * o4 + 1], a.y, s);
        fma4(acc[4 * o4 + 2], a.z, s);
        fma4(acc[4 * o4 + 3], a.w, s);
      }
    }
  }
  // ---- pass 2: x_l (64 channels), 4-channel groups with prefetch ----
  float4 n0 = xb[0], n1 = xb[16384], n2 = xb[2 * 16384], n3 = xb[3 * 16384];
  for (int ci = 0; ci < 64; ci += 4) {
    float4 c0 = n0, c1 = n1, c2 = n2, c3 = n3;
    if (ci < 60) {
      const float4* np = xb + (size_t)(ci + 4) * 16384;
      n0 = np[0]; n1 = np[16384]; n2 = np[2 * 16384]; n3 = np[3 * 16384];
    }
#pragma unroll
    for (int k = 0; k < 4; ++k) {
      float4 xl = (k == 0) ? c0 : (k == 1) ? c1 : (k == 2) ? c2 : c3;
      const float4* w4p = (const float4*)&wl[(ci + k) * 64 + og * 16];
#pragma unroll
      for (int o4 = 0; o4 < 4; ++o4) {
        float4 a = w4p[o4];
        fma4(acc[4 * o4 + 0], a.x, xl);
        fma4(acc[4 * o4 + 1], a.y, xl);
        fma4(acc[4 * o4 + 2], a.z, xl);
        fma4(acc[4 * o4 + 3], a.w, xl);
      }
    }
  }
  float4* ob = (float4*)out + (size_t)(b * 128 + og * 16) * 16384 + hw4;
#pragma unroll
  for (int o = 0; o < 16; ++o) ob[(size_t)o * 16384] = acc[o];
}

__global__ __launch_bounds__(256, 4) void final_fused(const float* __restrict__ x,
                          const float* __restrict__ y_g, const float* __restrict__ y2,
                          const float* __restrict__ w_out, const float* __restrict__ b_out,
                          const float* __restrict__ w_l2g, const float* __restrict__ b_l2g,
                          const float* __restrict__ w_local, const float* __restrict__ b_local,
                          const float* __restrict__ w_g2l, const float* __restrict__ b_g2l,
                          float* __restrict__ out) {
  __shared__ float sA[64 * 64], sB[64 * 64], sbb[64];
  const int t = threadIdx.x;
  const int isL = blockIdx.x & 1;
  const int pblk = blockIdx.x >> 1;
  if (isL) {
    for (int idx = t; idx < 4096; idx += 256) {
      sA[idx] = w_g2l[(idx & 63) * 64 + (idx >> 6)];
      sB[idx] = w_local[(idx & 63) * 64 + (idx >> 6)];
    }
    if (t < 64) sbb[t] = b_local[t] + b_g2l[t];
    __syncthreads();
    final_l_body(x, out, sA, sB, sbb, pblk, t);
  } else {
    for (int idx = t; idx < 2048; idx += 256) sA[idx] = w_out[(idx & 63) * 32 + (idx >> 6)];
    for (int idx = t; idx < 4096; idx += 256) sB[idx] = w_l2g[(idx & 63) * 64 + (idx >> 6)];
    if (t < 64) sbb[t] = b_out[t] + b_l2g[t];
    __syncthreads();
    final_g_body(x, y_g, y2, out, sA, sB, sbb, pblk, t);
  }
}

extern "C" void kernel_launch(void* const* d_in, const int* in_sizes, int n_in,
                              void* d_out, int out_size, void* d_ws, size_t ws_size,
                              hipStream_t stream) {
  (void)in_sizes; (void)n_in; (void)out_size; (void)ws_size;
  const float* x       = (const float*)d_in[0];
  const float* w_local = (const float*)d_in[1];
  const float* b_local = (const float*)d_in[2];
  const float* w_in    = (const float*)d_in[3];
  const float* b_in    = (const float*)d_in[4];
  const float* w_out   = (const float*)d_in[5];
  const float* b_out   = (const float*)d_in[6];
  const float* w_g2l   = (const float*)d_in[7];
  const float* b_g2l   = (const float*)d_in[8];
  const float* w_l2g   = (const float*)d_in[9];
  const float* b_l2g   = (const float*)d_in[10];
  const float* w_fu1   = (const float*)d_in[11];
  const float* b_fu1   = (const float*)d_in[12];
  const float* g_fu1   = (const float*)d_in[13];
  const float* be_fu1  = (const float*)d_in[14];
  const float* w_fu2   = (const float*)d_in[15];
  const float* b_fu2   = (const float*)d_in[16];
  const float* g_fu2   = (const float*)d_in[17];
  const float* be_fu2  = (const float*)d_in[18];
  float* out = (float*)d_out;

  // workspace layout (floats)
  float* ws   = (float*)d_ws;
  float* y_in = ws;                       // 8,388,608
  float* S1   = y_in + 8388608;           // 8,454,144 floats (spectral FU1; dead during bn_stats)
  float* Z1   = S1 + 8454144;             // 8,454,144 (y_g overlays after Z1 dead)
  float* y_g  = Z1;
  float* S2   = Z1 + 8454144;             // 2,129,920 floats
  float* Z2   = S2 + 2129920;             // 2,129,920 (y2 overlays)
  float* y2   = Z2;
  float* st1  = Z2 + 2129920;             // scale[64], shift[64]
  float* st2  = st1 + 128;
  double* pb1 = (double*)S1;              // 64*32*2 doubles, overlaid on dead S1
  double* pb2 = (double*)S2;

  conv_in_v<<<1024, 256, 0, stream>>>(x, w_in, b_in, y_in);

  // forward transforms (FU1 then FU2 fronts)
  rfft_rows<256, 8><<<32768, 128, 0, stream>>>(y_in, (float2*)S1);
  rfft_rows_lfu<<<16384, 64, 0, stream>>>(y_in, (float2*)S2);
  cfft_cols_t<256, 8, 16><<<128 * 9, 256, 0, stream>>>((float2*)S1, 129, -1.f, 9);
  cfft_cols_t<128, 7, 16><<<128 * 5, 256, 0, stream>>>((float2*)S2, 65, -1.f, 5);

  // fused spectral convs + BN stats/finalize
  conv_spec_fused<<<516 + 130, 256, 0, stream>>>((const float4*)S1, w_fu1, b_fu1, (float2*)Z1,
                                                 (const float4*)S2, w_fu2, b_fu2, (float2*)Z2);
  bn_stats_fused<<<4096, 256, 0, stream>>>(Z1, Z2, pb1, pb2);
  bn_finalize_fused<<<1, 128, 0, stream>>>(pb1, pb2, g_fu1, be_fu1, g_fu2, be_fu2, st1, st2);

  // inverse transforms
  cfft_inv_bn<256, 8, 16><<<128 * 9, 256, 0, stream>>>(Z1, st1, st1 + 64, (float2*)S1, 129, 9, 132096);
  cfft_inv_bn<128, 7, 16><<<128 * 5, 256, 0, stream>>>(Z2, st2, st2 + 64, (float2*)S2, 65, 5, 33280);
  irfft_rows<256, 8><<<32768, 128, 0, stream>>>((const float2*)S1, y_g, 1.f / 65536.f);
  irfft_rows<128, 7><<<16384, 64, 0, stream>>>((const float2*)S2, y2, 1.f / 16384.f);

  // fused epilogue: even blocks -> global-out path, odd blocks -> local-out path
  final_fused<<<2048, 256, 0, stream>>>(x, y_g, y2, w_out, b_out, w_l2g, b_l2g,
                                        w_local, b_local, w_g2l, b_g2l, out);
}

// Round 7
// 583.023 us; speedup vs baseline: 1.7556x; 1.0445x over previous
//
#include <hip/hip_runtime.h>
#include <math.h>

// FastFourierConvolution: B=4, C=128, H=W=256. Cg=Cl=64, Ci=32.
// FU1: (B,32,256,256) -> rfft2 -> conv64x64+BN+relu -> herm irfft2
// FU2 (LFU): y_in[:,24:32] quadrant-stacked to (B,32,128,128), same pipeline, tiled 2x2.
// R7: whole transform chain fused FU1+FU2 via block-range dispatch (proven R6 pattern):
// rfft(+lfu), cfft_cols, cfft_inv_bn, irfft each one kernel. 13 -> 9 launches.
// Math and per-row/tile accumulation order bit-identical to R6.

#define PI2 6.283185307179586f

__device__ __forceinline__ void fma4(float4& a, float w, const float4& v) {
  a.x += w * v.x; a.y += w * v.y; a.z += w * v.z; a.w += w * v.w;
}
__device__ __forceinline__ float4 add4(const float4& a, const float4& b) {
  return make_float4(a.x + b.x, a.y + b.y, a.z + b.z, a.w + b.w);
}

// ---------------- FFT core: radix-2 DIT in LDS ----------------
// tid in [0, N/2); syncthreads spans the whole block (over-sync across packed rows is fine:
// all packed rows run the identical stage schedule).
template<int N, int LOG2N>
__device__ __forceinline__ void fft_stages(float* re, float* im, int tid, float sign) {
#pragma unroll
  for (int s = 1; s <= LOG2N; ++s) {
    __syncthreads();
    const int half = 1 << (s - 1);
    const int j = tid & (half - 1);
    const int i1 = ((tid >> (s - 1)) << s) + j;
    const int i2 = i1 + half;
    float ang = sign * (PI2 / (float)(1 << s)) * (float)j;
    float wr, wi;
    __sincosf(ang, &wi, &wr);
    float xr = re[i2], xi = im[i2];
    float vr = xr * wr - xi * wi;
    float vi = xr * wi + xi * wr;
    float ur = re[i1], ui = im[i1];
    re[i1] = ur + vr; im[i1] = ui + vi;
    re[i2] = ur - vr; im[i2] = ui - vi;
  }
  __syncthreads();
}

// ---------------- fused row rfft: FU1 rows (N=256) + LFU rows (N=128, 2 per block) ------
__global__ void rfft_fused(const float* __restrict__ y_in,
                           float2* __restrict__ S1, float2* __restrict__ S2) {
  __shared__ float re[256], im[256];
  const int t = threadIdx.x;  // 128
  if (blockIdx.x < 32768) {
    const int row = blockIdx.x;
    const float* p = y_in + (size_t)row * 256;
    for (int i = t; i < 256; i += 128) {
      int j = __brev((unsigned)i) >> 24;
      re[j] = p[i];
      im[j] = 0.f;
    }
    fft_stages<256, 8>(re, im, t, -1.f);
    float2* q = S1 + (size_t)row * 129;
    for (int k = t; k <= 128; k += 128) q[k] = make_float2(re[k], im[k]);
  } else {
    const int sub = t >> 6, t64 = t & 63;
    const int row = (blockIdx.x - 32768) * 2 + sub;   // 16384 LFU rows
    const int h2 = row & 127;
    const int c2 = (row >> 7) & 31;
    const int b  = row >> 12;
    const int q = c2 >> 3, ch = c2 & 7;
    const int hs = ((q >> 1) << 7) + h2;
    const int ws0 = (q & 1) << 7;
    const float* p = y_in + (((size_t)(b * 32 + 24 + ch) * 256 + hs) * 256 + ws0);
    float* r = &re[sub * 128];
    float* iv = &im[sub * 128];
    for (int i = t64; i < 128; i += 64) {
      int j = __brev((unsigned)i) >> 25;
      r[j] = p[i];
      iv[j] = 0.f;
    }
    fft_stages<128, 7>(r, iv, t64, -1.f);
    float2* qp = S2 + (size_t)row * 65;
    for (int k = t64; k <= 64; k += 64) qp[k] = make_float2(r[k], iv[k]);
  }
}

// ---------------- fused forward column FFT (flat [N][17] shared) ----------------
template<int N, int LOG2N>
__device__ __forceinline__ void cfft_cols_body(float2* __restrict__ data, int Wf, float sign,
                                               int tilesPerImg, int bid,
                                               float* __restrict__ re, float* __restrict__ im) {
  const int TW = 16;
  const int img = bid / tilesPerImg;
  const int k0 = (bid % tilesPerImg) * TW;
  const int cols = min(TW, Wf - k0);
  float2* base = data + (size_t)img * N * Wf + k0;
  const int t = threadIdx.x;
  const int c = t & (TW - 1);
  const int g = t >> 4;
  const bool act = (c < cols);
  for (int r = g; r < N; r += 16) {
    float2 v;
    if (act) v = base[(size_t)r * Wf + c];
    int j = __brev((unsigned)r) >> (32 - LOG2N);
    if (act) { re[j * 17 + c] = v.x; im[j * 17 + c] = v.y; }
  }
#pragma unroll
  for (int s = 1; s <= LOG2N; ++s) {
    __syncthreads();
    const int half = 1 << (s - 1);
    for (int bf = g; bf < N / 2; bf += 16) {
      if (!act) continue;
      const int j = bf & (half - 1);
      const int i1 = ((bf >> (s - 1)) << s) + j;
      const int i2 = i1 + half;
      float ang = sign * (PI2 / (float)(1 << s)) * (float)j;
      float wr, wi;
      __sincosf(ang, &wi, &wr);
      float xr = re[i2 * 17 + c], xi = im[i2 * 17 + c];
      float vr = xr * wr - xi * wi;
      float vi = xr * wi + xi * wr;
      float ur = re[i1 * 17 + c], ui = im[i1 * 17 + c];
      re[i1 * 17 + c] = ur + vr; im[i1 * 17 + c] = ui + vi;
      re[i2 * 17 + c] = ur - vr; im[i2 * 17 + c] = ui - vi;
    }
  }
  __syncthreads();
  for (int r = g; r < N; r += 16) {
    if (act) base[(size_t)r * Wf + c] = make_float2(re[r * 17 + c], im[r * 17 + c]);
  }
}

__global__ void cfft_cols_fused(float2* __restrict__ d1, float2* __restrict__ d2) {
  __shared__ float re[256 * 17], im[256 * 17];
  if (blockIdx.x < 1152)
    cfft_cols_body<256, 8>(d1, 129, -1.f, 9, blockIdx.x, re, im);
  else
    cfft_cols_body<128, 7>(d2, 65, -1.f, 5, blockIdx.x - 1152, re, im);
}

// ---------------- fused BN+relu+symmetrize + inverse column FFT ----------------
template<int N, int LOG2N>
__device__ __forceinline__ void cfft_inv_body(const float* __restrict__ Z,
                            const float* __restrict__ scale, const float* __restrict__ shift,
                            float2* __restrict__ T, int Wf, int tilesPerImg, int chs, int bid,
                            float* __restrict__ re, float* __restrict__ im) {
  const int TW = 16;
  const int img = bid / tilesPerImg;    // b*32 + cc
  const int b = img >> 5, cc = img & 31;
  const int k0 = (bid % tilesPerImg) * TW;
  const int cols = min(TW, Wf - k0);
  const int t = threadIdx.x;
  const int c = t & (TW - 1);
  const int g = t >> 4;
  const bool act = (c < cols);
  const int kk = k0 + c;
  const float scr = scale[cc], sfr = shift[cc];
  const float sci = scale[cc + 32], sfi = shift[cc + 32];
  const float* Zr = Z + (size_t)cc * chs + (size_t)b * N * Wf;
  const float* Zi = Z + (size_t)(cc + 32) * chs + (size_t)b * N * Wf;
  const bool edge = (kk == 0 || kk == Wf - 1);
  for (int r = g; r < N; r += 16) {
    float vr = 0.f, vi = 0.f;
    if (act) {
      size_t p = (size_t)r * Wf + kk;
      float yr = fmaxf(Zr[p] * scr + sfr, 0.f);
      float yi = fmaxf(Zi[p] * sci + sfi, 0.f);
      if (edge) {
        int rm = (N - r) & (N - 1);
        size_t pm = (size_t)rm * Wf + kk;
        float yr2 = fmaxf(Zr[pm] * scr + sfr, 0.f);
        float yi2 = fmaxf(Zi[pm] * sci + sfi, 0.f);
        yr = 0.5f * (yr + yr2);
        yi = 0.5f * (yi - yi2);
      }
      vr = yr; vi = yi;
    }
    int j = __brev((unsigned)r) >> (32 - LOG2N);
    if (act) { re[j * 17 + c] = vr; im[j * 17 + c] = vi; }
  }
#pragma unroll
  for (int s = 1; s <= LOG2N; ++s) {
    __syncthreads();
    const int half = 1 << (s - 1);
    for (int bf = g; bf < N / 2; bf += 16) {
      if (!act) continue;
      const int jq = bf & (half - 1);
      const int i1 = ((bf >> (s - 1)) << s) + jq;
      const int i2 = i1 + half;
      float ang = (PI2 / (float)(1 << s)) * (float)jq;
      float wr, wi;
      __sincosf(ang, &wi, &wr);
      float xr = re[i2 * 17 + c], xi = im[i2 * 17 + c];
      float pr = xr * wr - xi * wi;
      float pi = xr * wi + xi * wr;
      float ur = re[i1 * 17 + c], ui = im[i1 * 17 + c];
      re[i1 * 17 + c] = ur + pr; im[i1 * 17 + c] = ui + pi;
      re[i2 * 17 + c] = ur - pr; im[i2 * 17 + c] = ui - pi;
    }
  }
  __syncthreads();
  float2* base = T + (size_t)img * N * Wf + k0;
  for (int r = g; r < N; r += 16)
    if (act) base[(size_t)r * Wf + c] = make_float2(re[r * 17 + c], im[r * 17 + c]);
}

__global__ void cfft_inv_fused(const float* __restrict__ Z1, const float* __restrict__ st1,
                               float2* __restrict__ T1,
                               const float* __restrict__ Z2, const float* __restrict__ st2,
                               float2* __restrict__ T2) {
  __shared__ float re[256 * 17], im[256 * 17];
  if (blockIdx.x < 1152)
    cfft_inv_body<256, 8>(Z1, st1, st1 + 64, T1, 129, 9, 132096, blockIdx.x, re, im);
  else
    cfft_inv_body<128, 7>(Z2, st2, st2 + 64, T2, 65, 5, 33280, blockIdx.x - 1152, re, im);
}

// ---------------- fused row irfft: FU1 (N=256) + FU2 (N=128, 2 rows/block) ----------
__global__ void irfft_fused(const float2* __restrict__ T1, float* __restrict__ y_g,
                            const float2* __restrict__ T2, float* __restrict__ y2) {
  __shared__ float re[256], im[256];
  const int t = threadIdx.x;  // 128
  if (blockIdx.x < 32768) {
    const int row = blockIdx.x;
    const float2* p = T1 + (size_t)row * 129;
    for (int i = t; i < 256; i += 128) {
      float2 v;
      if (i <= 128) v = p[i];
      else { v = p[256 - i]; v.y = -v.y; }
      int j = __brev((unsigned)i) >> 24;
      re[j] = v.x; im[j] = v.y;
    }
    fft_stages<256, 8>(re, im, t, 1.f);
    float* q = y_g + (size_t)row * 256;
    for (int i = t; i < 256; i += 128) q[i] = re[i] * (1.f / 65536.f);
  } else {
    const int sub = t >> 6, t64 = t & 63;
    const int row = (blockIdx.x - 32768) * 2 + sub;   // 16384 FU2 rows
    const float2* p = T2 + (size_t)row * 65;
    float* r = &re[sub * 128];
    float* iv = &im[sub * 128];
    for (int i = t64; i < 128; i += 64) {
      float2 v;
      if (i <= 64) v = p[i];
      else { v = p[128 - i]; v.y = -v.y; }
      int j = __brev((unsigned)i) >> 25;
      r[j] = v.x; iv[j] = v.y;
    }
    fft_stages<128, 7>(r, iv, t64, 1.f);
    float* q = y2 + (size_t)row * 128;
    for (int i = t64; i < 128; i += 64) q[i] = r[i] * (1.f / 16384.f);
  }
}

// ---------------- y_in = w_in(32x64) @ x[:, :64] + b_in (R1-proven) ----------------
__global__ __launch_bounds__(256, 4) void conv_in_v(const float* __restrict__ x,
                          const float* __restrict__ w,
                          const float* __restrict__ bias, float* __restrict__ y) {
  __shared__ float wt[32 * 64];  // wt[ci*32+o]
  __shared__ float bl[32];
  const int t = threadIdx.x;
  for (int idx = t; idx < 2048; idx += 256) wt[idx] = w[(idx & 31) * 64 + (idx >> 5)];
  if (t < 32) bl[t] = bias[t];
  __syncthreads();
  const int og = t >> 6;                       // 0..3 -> outputs og*8..og*8+7 (wave-uniform)
  const int p4 = blockIdx.x * 64 + (t & 63);   // 65536 float4-pixels
  const int hw4 = p4 & 16383;
  const int b = p4 >> 14;
  const float4* xb = (const float4*)x + (size_t)b * 128 * 16384 + hw4;
  float4 acc[8];
#pragma unroll
  for (int o = 0; o < 8; ++o) { float bv = bl[og * 8 + o]; acc[o] = make_float4(bv, bv, bv, bv); }
  float4 n0 = xb[0], n1 = xb[16384], n2 = xb[2 * 16384], n3 = xb[3 * 16384];
  for (int ci = 0; ci < 64; ci += 4) {
    float4 c0 = n0, c1 = n1, c2 = n2, c3 = n3;
    if (ci < 60) {
      const float4* np = xb + (size_t)(ci + 4) * 16384;
      n0 = np[0]; n1 = np[16384]; n2 = np[2 * 16384]; n3 = np[3 * 16384];
    }
#pragma unroll
    for (int k = 0; k < 4; ++k) {
      float4 v = (k == 0) ? c0 : (k == 1) ? c1 : (k == 2) ? c2 : c3;
      const float4* w4p = (const float4*)&wt[(ci + k) * 32 + og * 8];
      float4 a = w4p[0], c = w4p[1];
      fma4(acc[0], a.x, v); fma4(acc[1], a.y, v); fma4(acc[2], a.z, v); fma4(acc[3], a.w, v);
      fma4(acc[4], c.x, v); fma4(acc[5], c.y, v); fma4(acc[6], c.z, v); fma4(acc[7], c.w, v);
    }
  }
  float4* yb = (float4*)y + (size_t)(b * 32 + og * 8) * 16384 + hw4;
#pragma unroll
  for (int o = 0; o < 8; ++o) yb[(size_t)o * 16384] = acc[o];
}

// ---------------- spectral conv body (R1-proven), fused FU1+FU2 dispatch ----------------
template<int B_, int H_, int Wf_>
__device__ __forceinline__ void conv_spec_body(const float4* __restrict__ S4,
                            const float* __restrict__ w, const float* __restrict__ bias,
                            float2* __restrict__ Z2, int bid, float* wt, float* bl) {
  constexpr int PP = H_ * Wf_ / 2;      // complex pairs per (b,ci) plane
  constexpr int CHS2 = B_ * PP;         // pairs per out-channel
  const int t = threadIdx.x;
  for (int idx = t; idx < 4096; idx += 256) wt[idx] = w[(idx & 63) * 64 + (idx >> 6)];
  if (t < 64) bl[t] = bias[t];
  __syncthreads();
  const int og = t >> 7;                        // 0/1 -> 32 outputs (wave-uniform)
  const int j2 = bid * 128 + (t & 127);         // global pair index
  const int b = j2 / PP;
  const int jp = j2 - b * PP;
  float2 acc[32];
#pragma unroll
  for (int o = 0; o < 32; ++o) { float bv = bl[og * 32 + o]; acc[o] = make_float2(bv, bv); }
  const float4* sp = S4 + (size_t)(b * 32) * PP + jp;
  float4 nv = sp[0];
  for (int ci = 0; ci < 32; ++ci) {
    float4 sv = nv;                      // two complex: (x,y) (z,w)
    if (ci < 31) nv = sp[(size_t)(ci + 1) * PP];
    const float4* wr4 = (const float4*)&wt[ci * 64 + og * 32];
    const float4* wi4 = (const float4*)&wt[(ci + 32) * 64 + og * 32];
#pragma unroll
    for (int o4 = 0; o4 < 8; ++o4) {
      float4 a = wr4[o4], c = wi4[o4];
      acc[4 * o4 + 0].x += a.x * sv.x + c.x * sv.y;  acc[4 * o4 + 0].y += a.x * sv.z + c.x * sv.w;
      acc[4 * o4 + 1].x += a.y * sv.x + c.y * sv.y;  acc[4 * o4 + 1].y += a.y * sv.z + c.y * sv.w;
      acc[4 * o4 + 2].x += a.z * sv.x + c.z * sv.y;  acc[4 * o4 + 2].y += a.z * sv.z + c.z * sv.w;
      acc[4 * o4 + 3].x += a.w * sv.x + c.w * sv.y;  acc[4 * o4 + 3].y += a.w * sv.z + c.w * sv.w;
    }
  }
#pragma unroll
  for (int o = 0; o < 32; ++o) Z2[(size_t)(og * 32 + o) * CHS2 + j2] = acc[o];
}

__global__ __launch_bounds__(256, 4) void conv_spec_fused(
    const float4* __restrict__ S1, const float* __restrict__ w1, const float* __restrict__ b1,
    float2* __restrict__ Z1,
    const float4* __restrict__ S2, const float* __restrict__ w2, const float* __restrict__ b2,
    float2* __restrict__ Z2) {
  __shared__ float wt[4096];
  __shared__ float bl[64];
  if (blockIdx.x < 516)
    conv_spec_body<4, 256, 129>(S1, w1, b1, Z1, blockIdx.x, wt, bl);
  else
    conv_spec_body<4, 128, 65>(S2, w2, b2, Z2, blockIdx.x - 516, wt, bl);
}

// ---------------- BN stats fused (FU1: 2048 blocks, FU2: 2048 blocks) ----------------
__global__ void bn_stats_fused(const float* __restrict__ Z1, const float* __restrict__ Z2,
                               double* __restrict__ pb1, double* __restrict__ pb2) {
  int bid = blockIdx.x;
  const float* Z; double* pb; int chunk;
  if (bid < 2048) { Z = Z1; pb = pb1; chunk = 4128; }
  else { bid -= 2048; Z = Z2; pb = pb2; chunk = 1040; }
  const int c = bid >> 5;
  const int sl = bid & 31;
  const float* p = Z + (size_t)c * ((size_t)chunk * 32) + (size_t)sl * chunk;
  double s = 0.0, s2 = 0.0;
  for (int i = threadIdx.x; i < chunk; i += 256) {
    float v = p[i];
    s += v;
    s2 += (double)v * (double)v;
  }
  __shared__ double sh[256], sh2[256];
  sh[threadIdx.x] = s; sh2[threadIdx.x] = s2;
  __syncthreads();
  for (int off = 128; off > 0; off >>= 1) {
    if (threadIdx.x < off) { sh[threadIdx.x] += sh[threadIdx.x + off]; sh2[threadIdx.x] += sh2[threadIdx.x + off]; }
    __syncthreads();
  }
  if (threadIdx.x == 0) { pb[2 * bid] = sh[0]; pb[2 * bid + 1] = sh2[0]; }
}

__global__ void bn_finalize_fused(const double* __restrict__ pb1, const double* __restrict__ pb2,
                                  const float* __restrict__ g1, const float* __restrict__ be1,
                                  const float* __restrict__ g2, const float* __restrict__ be2,
                                  float* __restrict__ st1, float* __restrict__ st2) {
  const int t = threadIdx.x;  // 128 threads: 0-63 FU1, 64-127 FU2
  const bool fu1 = (t < 64);
  const double* pb = fu1 ? pb1 : pb2;
  const int n = fu1 ? 132096 : 33280;
  const float* gamma = fu1 ? g1 : g2;
  const float* beta  = fu1 ? be1 : be2;
  float* scale = fu1 ? st1 : st2;
  float* shift = fu1 ? (st1 + 64) : (st2 + 64);
  const int c = t & 63;
  double s = 0.0, s2 = 0.0;
  for (int i = 0; i < 32; ++i) { s += pb[2 * (c * 32 + i)]; s2 += pb[2 * (c * 32 + i) + 1]; }
  double mu = s / (double)n;
  double var = s2 / (double)n - mu * mu;
  float rs = (float)(1.0 / sqrt(var + 1e-5));
  float g = gamma[c] * rs;
  scale[c] = g;
  shift[c] = beta[c] - (float)mu * g;
}

// ---------------- fused epilogue: R1-proven bodies, parity block-split ----------------
__device__ __forceinline__ void final_l_body(const float* __restrict__ x, float* __restrict__ out,
                                             const float* wg, const float* wl, const float* bb,
                                             int pblk, int t) {
  const int og = t >> 6;                       // 16 outputs
  const int p4 = pblk * 64 + (t & 63);
  const int hw4 = p4 & 16383;
  const int b = p4 >> 14;
  const float4* xb = (const float4*)x + (size_t)b * 128 * 16384 + hw4;
  float4 acc[16];
#pragma unroll
  for (int o = 0; o < 16; ++o) { float bv = bb[og * 16 + o]; acc[o] = make_float4(bv, bv, bv, bv); }
  float4 g0 = xb[0], g1 = xb[16384];
  float4 l0 = xb[(size_t)64 * 16384], l1 = xb[(size_t)65 * 16384];
  for (int ci = 0; ci < 64; ci += 2) {
    float4 cg0 = g0, cg1 = g1, cl0 = l0, cl1 = l1;
    if (ci < 62) {
      const float4* np = xb + (size_t)(ci + 2) * 16384;
      g0 = np[0]; g1 = np[16384];
      l0 = np[(size_t)64 * 16384]; l1 = np[(size_t)65 * 16384];
    }
#pragma unroll
    for (int k = 0; k < 2; ++k) {
      float4 xg = k ? cg1 : cg0;
      float4 xl = k ? cl1 : cl0;
      const float4* g4 = (const float4*)&wg[(ci + k) * 64 + og * 16];
      const float4* l4 = (const float4*)&wl[(ci + k) * 64 + og * 16];
#pragma unroll
      for (int o4 = 0; o4 < 4; ++o4) {
        float4 a = g4[o4], cw = l4[o4];
        fma4(acc[4 * o4 + 0], a.x, xg); fma4(acc[4 * o4 + 0], cw.x, xl);
        fma4(acc[4 * o4 + 1], a.y, xg); fma4(acc[4 * o4 + 1], cw.y, xl);
        fma4(acc[4 * o4 + 2], a.z, xg); fma4(acc[4 * o4 + 2], cw.z, xl);
        fma4(acc[4 * o4 + 3], a.w, xg); fma4(acc[4 * o4 + 3], cw.w, xl);
      }
    }
  }
  float4* ob = (float4*)out + (size_t)(b * 128 + 64 + og * 16) * 16384 + hw4;
#pragma unroll
  for (int o = 0; o < 16; ++o) ob[(size_t)o * 16384] = acc[o];
}

__device__ __forceinline__ void final_g_body(const float* __restrict__ x,
                                             const float* __restrict__ y_g, const float* __restrict__ y2,
                                             float* __restrict__ out,
                                             const float* wo, const float* wl, const float* bb,
                                             int pblk, int t) {
  const int og = t >> 6;                       // 16 outputs
  const int p4 = pblk * 64 + (t & 63);
  const int hw4 = p4 & 16383;
  const int b = p4 >> 14;
  const int h = hw4 >> 6;                      // 64 float4 per row
  const int w4 = hw4 & 63;
  const int hw2_4 = ((h & 127) << 5) + (w4 & 31);
  const float4* xb = (const float4*)x + (size_t)(b * 128 + 64) * 16384 + hw4;
  const float4* gb = (const float4*)y_g + (size_t)b * 32 * 16384 + hw4;
  const float4* tb = (const float4*)y2 + (size_t)b * 32 * 4096 + hw2_4;
  float4 acc[16];
#pragma unroll
  for (int o = 0; o < 16; ++o) { float bv = bb[og * 16 + o]; acc[o] = make_float4(bv, bv, bv, bv); }
  // ---- pass 1: s = y_g + y2 (32 channels), 2-channel groups with prefetch ----
  float4 pg0 = gb[0], pg1 = gb[16384];
  float4 pt0 = tb[0], pt1 = tb[4096];
  for (int ci = 0; ci < 32; ci += 2) {
    float4 s0 = add4(pg0, pt0), s1 = add4(pg1, pt1);
    if (ci < 30) {
      const float4* gp = gb + (size_t)(ci + 2) * 16384;
      const float4* tp = tb + (size_t)(ci + 2) * 4096;
      pg0 = gp[0]; pg1 = gp[16384];
      pt0 = tp[0]; pt1 = tp[4096];
    }
#pragma unroll
    for (int k = 0; k < 2; ++k) {
      float4 s = k ? s1 : s0;
      const float4* w4p = (const float4*)&wo[(ci + k) * 64 + og * 16];
#pragma unroll
      for (int o4 = 0; o4 < 4; ++o4) {
        float4 a = w4p[o4];
        fma4(acc[4 * o4 + 0], a.x, s);
        fma4(acc[4 * o4 + 1], a.y, s);
        fma4(acc[4 * o4 + 2], a.z, s);
        fma4(acc[4 * o4 + 3], a.w, s);
      }
    }
  }
  // ---- pass 2: x_l (64 channels), 4-channel groups with prefetch ----
  float4 n0 = xb[0], n1 = xb[16384], n2 = xb[2 * 16384], n3 = xb[3 * 16384];
  for (int ci = 0; ci < 64; ci += 4) {
    float4 c0 = n0, c1 = n1, c2 = n2, c3 = n3;
    if (ci < 60) {
      const float4* np = xb + (size_t)(ci + 4) * 16384;
      n0 = np[0]; n1 = np[16384]; n2 = np[2 * 16384]; n3 = np[3 * 16384];
    }
#pragma unroll
    for (int k = 0; k < 4; ++k) {
      float4 xl = (k == 0) ? c0 : (k == 1) ? c1 : (k == 2) ? c2 : c3;
      const float4* w4p = (const float4*)&wl[(ci + k) * 64 + og * 16];
#pragma unroll
      for (int o4 = 0; o4 < 4; ++o4) {
        float4 a = w4p[o4];
        fma4(acc[4 * o4 + 0], a.x, xl);
        fma4(acc[4 * o4 + 1], a.y, xl);
        fma4(acc[4 * o4 + 2], a.z, xl);
        fma4(acc[4 * o4 + 3], a.w, xl);
      }
    }
  }
  float4* ob = (float4*)out + (size_t)(b * 128 + og * 16) * 16384 + hw4;
#pragma unroll
  for (int o = 0; o < 16; ++o) ob[(size_t)o * 16384] = acc[o];
}

__global__ __launch_bounds__(256, 4) void final_fused(const float* __restrict__ x,
                          const float* __restrict__ y_g, const float* __restrict__ y2,
                          const float* __restrict__ w_out, const float* __restrict__ b_out,
                          const float* __restrict__ w_l2g, const float* __restrict__ b_l2g,
                          const float* __restrict__ w_local, const float* __restrict__ b_local,
                          const float* __restrict__ w_g2l, const float* __restrict__ b_g2l,
                          float* __restrict__ out) {
  __shared__ float sA[64 * 64], sB[64 * 64], sbb[64];
  const int t = threadIdx.x;
  const int isL = blockIdx.x & 1;
  const int pblk = blockIdx.x >> 1;
  if (isL) {
    for (int idx = t; idx < 4096; idx += 256) {
      sA[idx] = w_g2l[(idx & 63) * 64 + (idx >> 6)];
      sB[idx] = w_local[(idx & 63) * 64 + (idx >> 6)];
    }
    if (t < 64) sbb[t] = b_local[t] + b_g2l[t];
    __syncthreads();
    final_l_body(x, out, sA, sB, sbb, pblk, t);
  } else {
    for (int idx = t; idx < 2048; idx += 256) sA[idx] = w_out[(idx & 63) * 32 + (idx >> 6)];
    for (int idx = t; idx < 4096; idx += 256) sB[idx] = w_l2g[(idx & 63) * 64 + (idx >> 6)];
    if (t < 64) sbb[t] = b_out[t] + b_l2g[t];
    __syncthreads();
    final_g_body(x, y_g, y2, out, sA, sB, sbb, pblk, t);
  }
}

extern "C" void kernel_launch(void* const* d_in, const int* in_sizes, int n_in,
                              void* d_out, int out_size, void* d_ws, size_t ws_size,
                              hipStream_t stream) {
  (void)in_sizes; (void)n_in; (void)out_size; (void)ws_size;
  const float* x       = (const float*)d_in[0];
  const float* w_local = (const float*)d_in[1];
  const float* b_local = (const float*)d_in[2];
  const float* w_in    = (const float*)d_in[3];
  const float* b_in    = (const float*)d_in[4];
  const float* w_out   = (const float*)d_in[5];
  const float* b_out   = (const float*)d_in[6];
  const float* w_g2l   = (const float*)d_in[7];
  const float* b_g2l   = (const float*)d_in[8];
  const float* w_l2g   = (const float*)d_in[9];
  const float* b_l2g   = (const float*)d_in[10];
  const float* w_fu1   = (const float*)d_in[11];
  const float* b_fu1   = (const float*)d_in[12];
  const float* g_fu1   = (const float*)d_in[13];
  const float* be_fu1  = (const float*)d_in[14];
  const float* w_fu2   = (const float*)d_in[15];
  const float* b_fu2   = (const float*)d_in[16];
  const float* g_fu2   = (const float*)d_in[17];
  const float* be_fu2  = (const float*)d_in[18];
  float* out = (float*)d_out;

  // workspace layout (floats)
  float* ws   = (float*)d_ws;
  float* y_in = ws;                       // 8,388,608
  float* S1   = y_in + 8388608;           // 8,454,144 floats (spectral FU1; dead during bn_stats)
  float* Z1   = S1 + 8454144;             // 8,454,144 (y_g overlays after Z1 dead)
  float* y_g  = Z1;
  float* S2   = Z1 + 8454144;             // 2,129,920 floats
  float* Z2   = S2 + 2129920;             // 2,129,920 (y2 overlays)
  float* y2   = Z2;
  float* st1  = Z2 + 2129920;             // scale[64], shift[64]
  float* st2  = st1 + 128;
  double* pb1 = (double*)S1;              // 64*32*2 doubles, overlaid on dead S1
  double* pb2 = (double*)S2;

  conv_in_v<<<1024, 256, 0, stream>>>(x, w_in, b_in, y_in);

  // fused forward row transforms (FU1 rows + LFU rows)
  rfft_fused<<<32768 + 8192, 128, 0, stream>>>(y_in, (float2*)S1, (float2*)S2);
  // fused forward column transforms
  cfft_cols_fused<<<1152 + 640, 256, 0, stream>>>((float2*)S1, (float2*)S2);

  // fused spectral convs + BN stats/finalize
  conv_spec_fused<<<516 + 130, 256, 0, stream>>>((const float4*)S1, w_fu1, b_fu1, (float2*)Z1,
                                                 (const float4*)S2, w_fu2, b_fu2, (float2*)Z2);
  bn_stats_fused<<<4096, 256, 0, stream>>>(Z1, Z2, pb1, pb2);
  bn_finalize_fused<<<1, 128, 0, stream>>>(pb1, pb2, g_fu1, be_fu1, g_fu2, be_fu2, st1, st2);

  // fused inverse column transforms
  cfft_inv_fused<<<1152 + 640, 256, 0, stream>>>(Z1, st1, (float2*)S1, Z2, st2, (float2*)S2);
  // fused inverse row transforms
  irfft_fused<<<32768 + 8192, 128, 0, stream>>>((const float2*)S1, y_g, (const float2*)S2, y2);

  // fused epilogue: even blocks -> global-out path, odd blocks -> local-out path
  final_fused<<<2048, 256, 0, stream>>>(x, y_g, y2, w_out, b_out, w_l2g, b_l2g,
                                        w_local, b_local, w_g2l, b_g2l, out);
}